// Round 7
// baseline (988.351 us; speedup 1.0000x reference)
//
#include <hip/hip_runtime.h>
#include <math.h>

// Problem constants: B=4, S=1024, D=1024, H=16, DH=64, E=8, FF=2048
#define B_   4
#define S_   1024
#define D_   1024
#define H_   16
#define DH_  64
#define E_   8
#define FF_  2048
#define M_   (B_ * S_)     // 4096 rows
#define EPS_ 1e-5f

typedef _Float16 f16;
typedef f16  f16x8 __attribute__((ext_vector_type(8)));
typedef f16  f16x4 __attribute__((ext_vector_type(4)));
typedef float f32x4 __attribute__((ext_vector_type(4)));

// async global->LDS, 16B per lane. LDS dest is wave-uniform base
// (HW writes base + lane*16); global src is per-lane.
__device__ __forceinline__ void gl_lds16(const f16* g, f16* l) {
  __builtin_amdgcn_global_load_lds(
      (const __attribute__((address_space(1))) void*)g,
      (__attribute__((address_space(3))) void*)l, 16, 0, 0);
}

#define MODE_F32  0
#define MODE_QKV  1
#define MODE_MOE1 2
#define MODE_MOE2 3

// ============================================================================
// fp32 -> f16 elementwise convert (8 elems/thread)
// ============================================================================
__global__ __launch_bounds__(256) void cvt_f16(
    const float* __restrict__ in, f16* __restrict__ out, int n8) {
  int i = blockIdx.x * 256 + threadIdx.x;
  if (i >= n8) return;
  float4 u = ((const float4*)in)[(size_t)i * 2];
  float4 v = ((const float4*)in)[(size_t)i * 2 + 1];
  f16x8 o;
  o[0] = (f16)u.x; o[1] = (f16)u.y; o[2] = (f16)u.z; o[3] = (f16)u.w;
  o[4] = (f16)v.x; o[5] = (f16)v.y; o[6] = (f16)v.z; o[7] = (f16)v.w;
  *(f16x8*)&out[(size_t)i * 8] = o;
}

// ============================================================================
// Transposing convert: in fp32 [z][R][C] -> out f16 [z][C][R].
// ============================================================================
__global__ __launch_bounds__(256) void transpose_cvt(
    const float* __restrict__ in, f16* __restrict__ out, int R, int C) {
  __shared__ float t[32][33];
  in  += (size_t)blockIdx.z * R * C;
  out += (size_t)blockIdx.z * R * C;
  const int c0 = blockIdx.x * 32, r0 = blockIdx.y * 32;
  const int tx = threadIdx.x & 31, ty = threadIdx.x >> 5;  // ty 0..7
#pragma unroll
  for (int i = 0; i < 4; ++i)
    t[ty + 8 * i][tx] = in[(size_t)(r0 + ty + 8 * i) * C + c0 + tx];
  __syncthreads();
#pragma unroll
  for (int i = 0; i < 4; ++i)
    out[(size_t)(c0 + ty + 8 * i) * R + r0 + tx] = (f16)t[tx][ty + 8 * i];
}

// ============================================================================
// gemm2: 256x256 tile, BK=32, 8 waves (2Mx4N), per-wave 128x64 output.
// Double-buffered LDS (64 KB), raw s_barrier + counted vmcnt(4) so the
// global_load_lds prefetch stays in flight across barriers (no full drain).
// LDS rows 64 B (32 halves); 16B-slot swizzle: phys = logical ^ ((row>>1)&3)
// applied on BOTH sides (pre-swizzled global source, swizzled frag read) ->
// 2-way (free) bank aliasing on ds_read_b128.
//   MODE_QKV : C = f16(acc + bias[col])
//   MODE_MOE1: z=expert-in-slab; C[z] = f16(relu(acc+b1[e0+z][col])*gate)
//   MODE_MOE2: z=k-slice (512 of FF); C[z] f16 (+= when accum)
// ============================================================================
template<int MODE>
__global__ __launch_bounds__(512, 2) void gemm2(
    const f16* __restrict__ A, int lda,
    const f16* __restrict__ B, int ldb,
    const float* __restrict__ bias, const float* __restrict__ gates,
    f16* __restrict__ C, int N, int NT, int e0, int accum) {
  __shared__ f16 Ab[2 * 256 * 32];   // [buf][row][32 halves]
  __shared__ f16 Bb[2 * 256 * 32];
  const int tid = threadIdx.x;
  const int wid = tid >> 6, lane = tid & 63;
  const int wm = wid >> 2, wn = wid & 3;          // wave grid 2x4
  const int r16 = lane & 15, kg = lane >> 4;
  const int m0 = blockIdx.y * 256, n0 = blockIdx.x * 256;
  const int z = blockIdx.z;

  const f16* Ap = A;
  const f16* Bp = B;
  f16* Cp = C;
  if (MODE == MODE_MOE1) {
    Bp += (size_t)z * N * 1024;            // w1t plane (K=1024)
    Cp += (size_t)z * M_ * N;              // h plane
  }
  if (MODE == MODE_MOE2) {
    Ap += z * 512;                         // k-slice of FF
    Bp += z * 512;
    Cp += (size_t)z * M_ * N;              // ff partial plane
  }

  // staging: 512 threads x 16B = 8 KB unit = 128 rows; 2 units per operand.
  const int srow = tid >> 2;                       // row within unit
  const int sg   = (tid & 3) ^ ((tid >> 3) & 3);   // pre-swizzled 16B slot
  const f16* Asrc = Ap + (size_t)(m0 + srow) * lda + sg * 8;
  const f16* Bsrc = Bp + (size_t)(n0 + srow) * ldb + sg * 8;
  char* AbC = (char*)Ab;
  char* BbC = (char*)Bb;
  const int ldsW = wid * 1024;                     // wave segment in unit

#define STAGE2(tt, bb)                                                         \
  {                                                                            \
    gl_lds16(Asrc + (tt) * 32,                   (f16*)(AbC + (bb) * 16384 + ldsW));        \
    gl_lds16(Asrc + (size_t)128 * lda + (tt) * 32, (f16*)(AbC + (bb) * 16384 + 8192 + ldsW)); \
    gl_lds16(Bsrc + (tt) * 32,                   (f16*)(BbC + (bb) * 16384 + ldsW));        \
    gl_lds16(Bsrc + (size_t)128 * ldb + (tt) * 32, (f16*)(BbC + (bb) * 16384 + 8192 + ldsW)); \
  }

  // fragment-read bases (swizzled): bank = 16(r16&1) + 4(kg^((r16>>1)&3)) -> 2-way
  const int sswz = (kg ^ ((r16 >> 1) & 3)) * 16;
  const int aoff = (wm * 128 + r16) * 64 + sswz;   // + i*1024 + buf*16384
  const int boff = (wn * 64 + r16) * 64 + sswz;    // + j*1024 + buf*16384

  f32x4 acc[8][4] = {};
  STAGE2(0, 0);
  for (int t = 0; t < NT; ++t) {
    const int b = t & 1;
    if (t + 1 < NT) {
      STAGE2(t + 1, b ^ 1);
      asm volatile("s_waitcnt vmcnt(4)" ::: "memory");  // tile t landed; 4 newest fly
    } else {
      asm volatile("s_waitcnt vmcnt(0)" ::: "memory");
    }
    __builtin_amdgcn_sched_barrier(0);
    __builtin_amdgcn_s_barrier();      // all waves' tile-t data visible
    f16x8 af[8], bf[4];
#pragma unroll
    for (int i = 0; i < 8; ++i)
      af[i] = *(const f16x8*)(AbC + b * 16384 + aoff + i * 1024);
#pragma unroll
    for (int j = 0; j < 4; ++j)
      bf[j] = *(const f16x8*)(BbC + b * 16384 + boff + j * 1024);
    __builtin_amdgcn_s_setprio(1);
#pragma unroll
    for (int i = 0; i < 8; ++i)
#pragma unroll
      for (int j = 0; j < 4; ++j)
        acc[i][j] = __builtin_amdgcn_mfma_f32_16x16x32_f16(
            af[i], bf[j], acc[i][j], 0, 0, 0);
    __builtin_amdgcn_s_setprio(0);
    asm volatile("" ::: "memory");
    __builtin_amdgcn_sched_barrier(0);
    __builtin_amdgcn_s_barrier();      // reads of buf b done before overwrite
  }
#undef STAGE2

  // epilogue: C/D layout col=lane&15, row=(lane>>4)*4+reg
#pragma unroll
  for (int i = 0; i < 8; ++i) {
#pragma unroll
    for (int r = 0; r < 4; ++r) {
      const int row = m0 + wm * 128 + i * 16 + kg * 4 + r;
      float gsc = 0.f;
      if (MODE == MODE_MOE1) gsc = gates[(size_t)row * E_ + e0 + z];
#pragma unroll
      for (int j = 0; j < 4; ++j) {
        const int col = n0 + wn * 64 + j * 16 + r16;
        float v = acc[i][j][r];
        if (MODE == MODE_QKV) {
          Cp[(size_t)row * N + col] = (f16)(v + bias[col]);
        } else if (MODE == MODE_MOE1) {
          float tv = fmaxf(v + bias[(size_t)z * N + col], 0.f) * gsc;
          Cp[(size_t)row * N + col] = (f16)tv;
        } else {  // MODE_MOE2
          float o = v;
          if (accum) o += (float)Cp[(size_t)row * N + col];
          Cp[(size_t)row * N + col] = (f16)o;
        }
      }
    }
  }
}

// ============================================================================
// gemm16 (m97 structure, 128x128) — retained for out_proj (N=1024 keeps
// 512 blocks here vs 64 at 256^2). Writes f16 output (MODE_QKV semantics).
// ============================================================================
template<int MODE>
__global__ __launch_bounds__(256) void gemm16(
    const f16* __restrict__ A, const f16* __restrict__ B,
    const float* __restrict__ bias, f16* __restrict__ Ch, int N, int K) {
  __shared__ f16 Ah[128 * 64];
  __shared__ f16 Bh[128 * 64];
  const int tid = threadIdx.x;
  const int wid = tid >> 6, lane = tid & 63;
  const int wm = wid >> 1, wn = wid & 1;
  const int r16 = lane & 15, kg = lane >> 4;
  const int m0 = blockIdx.y * 128, n0 = blockIdx.x * 128;
  const int srow = lane >> 3;
  const int sslot = (lane & 7) ^ srow;

  char* AhB = (char*)Ah;
  char* BhB = (char*)Bh;
  const int rbA = (wm * 64 + r16) * 128;
  const int rbB = (wn * 64 + r16) * 128;
  const int sw0 = ((0 + kg) ^ (r16 & 7)) << 4;
  const int sw1 = ((4 + kg) ^ (r16 & 7)) << 4;

  f32x4 acc[4][4] = {};
  const f16* ApL = A + (size_t)(m0 + wid * 32 + srow) * K + sslot * 8;
  const f16* BpL = B + (size_t)(n0 + wid * 32 + srow) * K + sslot * 8;
  for (int k0 = 0; k0 < K; k0 += 64) {
    __syncthreads();
#pragma unroll
    for (int ia = 0; ia < 4; ++ia)
      gl_lds16(ApL + (size_t)ia * 8 * K + k0, (f16*)(AhB + (wid * 4 + ia) * 1024));
#pragma unroll
    for (int ib = 0; ib < 4; ++ib)
      gl_lds16(BpL + (size_t)ib * 8 * K + k0, (f16*)(BhB + (wid * 4 + ib) * 1024));
    __syncthreads();
#pragma unroll
    for (int ks = 0; ks < 2; ++ks) {
      const int sw = ks ? sw1 : sw0;
      f16x8 af[4], bf[4];
#pragma unroll
      for (int i = 0; i < 4; ++i)
        af[i] = *(const f16x8*)(AhB + rbA + i * 2048 + sw);
#pragma unroll
      for (int j = 0; j < 4; ++j)
        bf[j] = *(const f16x8*)(BhB + rbB + j * 2048 + sw);
#pragma unroll
      for (int i = 0; i < 4; ++i)
#pragma unroll
        for (int j = 0; j < 4; ++j)
          acc[i][j] = __builtin_amdgcn_mfma_f32_16x16x32_f16(
              af[i], bf[j], acc[i][j], 0, 0, 0);
    }
  }
#pragma unroll
  for (int i = 0; i < 4; ++i)
#pragma unroll
    for (int r = 0; r < 4; ++r) {
      const int row = m0 + wm * 64 + i * 16 + kg * 4 + r;
#pragma unroll
      for (int j = 0; j < 4; ++j) {
        const int col = n0 + wn * 64 + j * 16 + r16;
        Ch[(size_t)row * N + col] = (f16)(acc[i][j][r] + bias[col]);
      }
    }
}

// ============================================================================
// MFMA flash attention (unchanged from round 5: 89 us, passing).
// ============================================================================
__global__ __launch_bounds__(256) void attn_kernel(
    const f16* __restrict__ qkv, const unsigned char* __restrict__ kpm,
    f16* __restrict__ ctxh) {
  __shared__ f16 Qs[64][72];
  __shared__ f16 Ks[64][72];
  __shared__ f16 VTs[64][72];
  __shared__ f16 Ps[4][16][72];
  const int tid = threadIdx.x;
  const int w = tid >> 6, lane = tid & 63;
  const int cx = lane & 15, qg = lane >> 4;
  const int qt = blockIdx.x, h = blockIdx.y, b = blockIdx.z;
  const size_t base = (size_t)b * S_ * (3 * D_);
  const f16* Qg = qkv + base + h * 64;
  const f16* Kg = qkv + base + D_ + h * 64;
  const f16* Vg = qkv + base + 2 * D_ + h * 64;
  const int lr = tid >> 2, lc = (tid & 3) * 16;

  {
    const f16* sp = &Qg[(size_t)(qt * 64 + lr) * (3 * D_) + lc];
    *(f16x8*)&Qs[lr][lc]     = *(const f16x8*)&sp[0];
    *(f16x8*)&Qs[lr][lc + 8] = *(const f16x8*)&sp[8];
  }
  __syncthreads();
  f16x8 aq0 = *(const f16x8*)&Qs[w * 16 + cx][qg * 8];
  f16x8 aq1 = *(const f16x8*)&Qs[w * 16 + cx][32 + qg * 8];

  f32x4 accO[4] = {};
  float mrun[4], lrun[4];
#pragma unroll
  for (int r = 0; r < 4; ++r) { mrun[r] = -__builtin_inff(); lrun[r] = 0.f; }

  for (int kt = 0; kt < 16; ++kt) {
    __syncthreads();
    {
      const f16* ksp = &Kg[(size_t)(kt * 64 + lr) * (3 * D_) + lc];
      const f16* vsp = &Vg[(size_t)(kt * 64 + lr) * (3 * D_) + lc];
      *(f16x8*)&Ks[lr][lc]     = *(const f16x8*)&ksp[0];
      *(f16x8*)&Ks[lr][lc + 8] = *(const f16x8*)&ksp[8];
      f16x8 v0 = *(const f16x8*)&vsp[0];
      f16x8 v1 = *(const f16x8*)&vsp[8];
#pragma unroll
      for (int j = 0; j < 8; ++j) {
        VTs[lc + j][lr]     = v0[j];
        VTs[lc + 8 + j][lr] = v1[j];
      }
    }
    __syncthreads();
    f32x4 s[4];
#pragma unroll
    for (int t = 0; t < 4; ++t) {
      f16x8 bk0 = *(const f16x8*)&Ks[t * 16 + cx][qg * 8];
      f16x8 bk1 = *(const f16x8*)&Ks[t * 16 + cx][32 + qg * 8];
      f32x4 zz = {};
      zz = __builtin_amdgcn_mfma_f32_16x16x32_f16(aq0, bk0, zz, 0, 0, 0);
      zz = __builtin_amdgcn_mfma_f32_16x16x32_f16(aq1, bk1, zz, 0, 0, 0);
      s[t] = zz;
    }
    const unsigned char* mp = &kpm[(size_t)b * S_ + kt * 64];
    bool mk[4];
#pragma unroll
    for (int t = 0; t < 4; ++t) mk[t] = mp[t * 16 + cx] != 0;
#pragma unroll
    for (int r = 0; r < 4; ++r) {
      float sv[4];
#pragma unroll
      for (int t = 0; t < 4; ++t)
        sv[t] = mk[t] ? -__builtin_inff() : s[t][r] * 0.125f;
      float mx = fmaxf(fmaxf(sv[0], sv[1]), fmaxf(sv[2], sv[3]));
#pragma unroll
      for (int mm = 1; mm < 16; mm <<= 1) mx = fmaxf(mx, __shfl_xor(mx, mm, 64));
      float mnew = fmaxf(mrun[r], mx);
      float al = (mrun[r] == -__builtin_inff()) ? 0.f : __expf(mrun[r] - mnew);
      float ps = 0.f;
#pragma unroll
      for (int t = 0; t < 4; ++t) {
        float p = __expf(sv[t] - mnew);
        Ps[w][qg * 4 + r][t * 16 + cx] = (f16)p;
        ps += p;
      }
#pragma unroll
      for (int mm = 1; mm < 16; mm <<= 1) ps += __shfl_xor(ps, mm, 64);
      lrun[r] = lrun[r] * al + ps;
      mrun[r] = mnew;
#pragma unroll
      for (int t = 0; t < 4; ++t) accO[t][r] *= al;
    }
    f16x8 ap0 = *(const f16x8*)&Ps[w][cx][qg * 8];
    f16x8 ap1 = *(const f16x8*)&Ps[w][cx][32 + qg * 8];
#pragma unroll
    for (int td = 0; td < 4; ++td) {
      f16x8 bv0 = *(const f16x8*)&VTs[td * 16 + cx][qg * 8];
      f16x8 bv1 = *(const f16x8*)&VTs[td * 16 + cx][32 + qg * 8];
      accO[td] = __builtin_amdgcn_mfma_f32_16x16x32_f16(ap0, bv0, accO[td], 0, 0, 0);
      accO[td] = __builtin_amdgcn_mfma_f32_16x16x32_f16(ap1, bv1, accO[td], 0, 0, 0);
    }
  }
  f16* outp = ctxh + (size_t)b * S_ * D_ + h * 64;
#pragma unroll
  for (int r = 0; r < 4; ++r) {
    float inv = 1.f / lrun[r];
    const size_t rofs = (size_t)(qt * 64 + w * 16 + qg * 4 + r) * D_;
#pragma unroll
    for (int td = 0; td < 4; ++td)
      outp[rofs + td * 16 + cx] = (f16)(accO[td][r] * inv);
  }
}

// ============================================================================
// Residual add + LayerNorm. Sums `nparts` f16 planes; optional gates·b2;
// optional f16 mirror. One block per row.
// ============================================================================
__global__ __launch_bounds__(256) void add_ln(
    const float* __restrict__ x1, const f16* __restrict__ parts, int nparts,
    const float* __restrict__ gates, const float* __restrict__ b2,
    const float* __restrict__ g, const float* __restrict__ bta,
    float* __restrict__ out, f16* __restrict__ outh) {
  __shared__ float red[4];
  const int row = blockIdx.x, tid = threadIdx.x;
  const size_t off = (size_t)row * D_ + tid * 4;
  float4 a = *(const float4*)&x1[off];
  float v[4] = {a.x, a.y, a.z, a.w};
  for (int p = 0; p < nparts; ++p) {
    f16x4 c = *(const f16x4*)&parts[(size_t)p * M_ * D_ + off];
    v[0] += (float)c[0]; v[1] += (float)c[1];
    v[2] += (float)c[2]; v[3] += (float)c[3];
  }
  if (gates) {
#pragma unroll
    for (int e = 0; e < E_; ++e) {
      float ge = gates[(size_t)row * E_ + e];
      float4 bb = *(const float4*)&b2[(size_t)e * D_ + tid * 4];
      v[0] += ge * bb.x; v[1] += ge * bb.y; v[2] += ge * bb.z; v[3] += ge * bb.w;
    }
  }
  float p = v[0] + v[1] + v[2] + v[3];
#pragma unroll
  for (int mm = 32; mm >= 1; mm >>= 1) p += __shfl_xor(p, mm, 64);
  if ((tid & 63) == 0) red[tid >> 6] = p;
  __syncthreads();
  float mu = (red[0] + red[1] + red[2] + red[3]) * (1.f / D_);
  __syncthreads();
  float d0 = v[0] - mu, d1 = v[1] - mu, d2 = v[2] - mu, d3 = v[3] - mu;
  float p2 = d0 * d0 + d1 * d1 + d2 * d2 + d3 * d3;
#pragma unroll
  for (int mm = 32; mm >= 1; mm >>= 1) p2 += __shfl_xor(p2, mm, 64);
  if ((tid & 63) == 0) red[tid >> 6] = p2;
  __syncthreads();
  float var = (red[0] + red[1] + red[2] + red[3]) * (1.f / D_);
  float sc = rsqrtf(var + EPS_);
  float4 gg = *(const float4*)&g[tid * 4];
  float4 bb = *(const float4*)&bta[tid * 4];
  float o0 = d0 * sc * gg.x + bb.x;
  float o1 = d1 * sc * gg.y + bb.y;
  float o2 = d2 * sc * gg.z + bb.z;
  float o3 = d3 * sc * gg.w + bb.w;
  float4 o = {o0, o1, o2, o3};
  *(float4*)&out[off] = o;
  if (outh) {
    f16x4 oh; oh[0] = (f16)o0; oh[1] = (f16)o1; oh[2] = (f16)o2; oh[3] = (f16)o3;
    *(f16x4*)&outh[off] = oh;
  }
}

// ============================================================================
// MoE gate: softmax(x @ gate_w^T + gate_b). One wave per row.
// ============================================================================
__global__ __launch_bounds__(256) void gate_kernel(
    const float* __restrict__ x, const float* __restrict__ gw,
    const float* __restrict__ gb, float* __restrict__ gates) {
  const int lane = threadIdx.x & 63;
  const int row = blockIdx.x * 4 + (threadIdx.x >> 6);
  const float* xr = x + (size_t)row * D_;
  float a[E_] = {};
#pragma unroll
  for (int c = 0; c < 4; ++c) {
    float4 xv = *(const float4*)&xr[lane * 16 + c * 4];
#pragma unroll
    for (int e = 0; e < E_; ++e) {
      float4 wv = *(const float4*)&gw[(size_t)e * D_ + lane * 16 + c * 4];
      a[e] += xv.x * wv.x + xv.y * wv.y + xv.z * wv.z + xv.w * wv.w;
    }
  }
#pragma unroll
  for (int e = 0; e < E_; ++e) {
#pragma unroll
    for (int mm = 1; mm < 64; mm <<= 1) a[e] += __shfl_xor(a[e], mm, 64);
    a[e] += gb[e];
  }
  if (lane == 0) {
    float mx = a[0];
#pragma unroll
    for (int e = 1; e < E_; ++e) mx = fmaxf(mx, a[e]);
    float pr[E_], sum = 0.f;
#pragma unroll
    for (int e = 0; e < E_; ++e) { pr[e] = __expf(a[e] - mx); sum += pr[e]; }
    float inv = 1.f / sum;
#pragma unroll
    for (int e = 0; e < E_; ++e) gates[(size_t)row * E_ + e] = pr[e] * inv;
  }
}

// ============================================================================
extern "C" void kernel_launch(void* const* d_in, const int* in_sizes, int n_in,
                              void* d_out, int out_size, void* d_ws, size_t ws_size,
                              hipStream_t stream) {
  (void)in_sizes; (void)n_in; (void)out_size; (void)ws_size;
  const float* src         = (const float*)d_in[0];
  const unsigned char* kpm = (const unsigned char*)d_in[1];
  const float* in_proj_w   = (const float*)d_in[2];
  const float* in_proj_b   = (const float*)d_in[3];
  const float* out_proj_w  = (const float*)d_in[4];
  const float* out_proj_b  = (const float*)d_in[5];
  const float* gate_w      = (const float*)d_in[6];
  const float* gate_b      = (const float*)d_in[7];
  const float* w1          = (const float*)d_in[8];
  const float* b1          = (const float*)d_in[9];
  const float* w2          = (const float*)d_in[10];
  const float* b2          = (const float*)d_in[11];
  const float* ln1_g       = (const float*)d_in[12];
  const float* ln1_b       = (const float*)d_in[13];
  const float* ln2_g       = (const float*)d_in[14];
  const float* ln2_b       = (const float*)d_in[15];
  float* out = (float*)d_out;

  // Workspace (100.8 MB total; proven-available 105.5 MB small-path budget):
  //   persist: x_ (16), x_h (8), gts (0.13)
  //   region (72 MB, overlaid):
  //     phase A: src_h 8 | ipw 6 | opw 2 | qkvh 24 | ctxh 8  (aout_h = src_h)
  //     MoE    : wts 8 (w1t then w2t) | h2 32 | ff4 32
  char* p = (char*)d_ws;
  float* x_  = (float*)p;  p += (size_t)M_ * D_ * 4;
  f16*   x_h = (f16*)p;    p += (size_t)M_ * D_ * 2;
  float* gts = (float*)p;  p += (size_t)M_ * E_ * 4;
  char* region = p;

  f16*   src_h = (f16*)region;
  f16*   ipw   = (f16*)(region + 8388608);
  f16*   opw   = (f16*)(region + 8388608 + 6291456);
  f16*   qkvh  = (f16*)(region + 8388608 + 6291456 + 2097152);
  f16*   ctxh  = (f16*)(region + 8388608 + 6291456 + 2097152 + 25165824);
  f16*   aouth = src_h;  // src_h dead after qkv projection

  f16*   wts = (f16*)region;                    // 8.39 MB (2 experts)
  f16*   h2  = (f16*)(region + 8388608);        // [2][M][FF] f16, 33.5 MB
  f16*   ff4 = (f16*)(region + 8388608 + 33554432);  // [4][M][D] f16, 33.5 MB

  dim3 blk(256), blk2(512);
  // --- prep ---
  cvt_f16<<<2048, blk, 0, stream>>>(src, src_h, M_ * D_ / 8);
  cvt_f16<<<1536, blk, 0, stream>>>(in_proj_w, ipw, 3 * D_ * D_ / 8);
  cvt_f16<<<512,  blk, 0, stream>>>(out_proj_w, opw, D_ * D_ / 8);
  // --- attention phase ---
  gemm2<MODE_QKV><<<dim3(12, 16), blk2, 0, stream>>>(
      src_h, D_, ipw, D_, in_proj_b, nullptr, qkvh, 3 * D_, 32, 0, 0);
  attn_kernel<<<dim3(S_ / 64, H_, B_), blk, 0, stream>>>(qkvh, kpm, ctxh);
  gemm16<MODE_QKV><<<dim3(8, 32), blk, 0, stream>>>(
      ctxh, opw, out_proj_b, aouth, D_, D_);
  add_ln<<<M_, blk, 0, stream>>>(src, aouth, 1, nullptr, nullptr,
                                 ln1_g, ln1_b, x_, x_h);
  gate_kernel<<<M_ / 4, blk, 0, stream>>>(x_, gate_w, gate_b, gts);
  // --- MoE phase: 4 slabs of 2 experts ---
  for (int pp = 0; pp < 4; ++pp) {
    const int e0 = 2 * pp;
    // w1 slab [2][D][FF] -> w1t [2][FF][D]
    transpose_cvt<<<dim3(FF_ / 32, D_ / 32, 2), blk, 0, stream>>>(
        w1 + (size_t)e0 * D_ * FF_, wts, D_, FF_);
    gemm2<MODE_MOE1><<<dim3(8, 16, 2), blk2, 0, stream>>>(
        x_h, D_, wts, D_, b1 + (size_t)e0 * FF_, gts, h2, FF_, 32, e0, 0);
    // w2 slab [2][FF][D] -> w2t [2][D][FF]  (reuse wts; w1t dead)
    transpose_cvt<<<dim3(D_ / 32, FF_ / 32, 2), blk, 0, stream>>>(
        w2 + (size_t)e0 * FF_ * D_, wts, FF_, D_);
    for (int e2 = 0; e2 < 2; ++e2) {
      gemm2<MODE_MOE2><<<dim3(4, 16, 4), blk2, 0, stream>>>(
          h2 + (size_t)e2 * M_ * FF_, FF_, wts + (size_t)e2 * D_ * FF_, FF_,
          nullptr, nullptr, ff4, D_, 16, 0, (pp > 0 || e2 > 0) ? 1 : 0);
    }
  }
  // --- out = LN2(x + sum ff4 + sum_e gates*b2[e]) ---
  add_ln<<<M_, blk, 0, stream>>>(x_, ff4, 4, gts, b2, ln2_g, ln2_b, out, nullptr);
}